// Round 7
// baseline (431.653 us; speedup 1.0000x reference)
//
#include <hip/hip_runtime.h>

#define D 128
#define R 8  // atomic-target replication factor

// ---------------------------------------------------------------- utilities
__global__ void zero_u32(unsigned* p, int n) {
  int i = blockIdx.x * blockDim.x + threadIdx.x;
  int stride = gridDim.x * blockDim.x;
  for (; i < n; i += stride) p[i] = 0u;
}

// Replicated degree count: replica = blockIdx & (R-1).
// rep layout: [R][2N] = [r][cnt_out(N) | cnt_in(N)]
__global__ void count_deg_rep(const int* __restrict__ src, const int* __restrict__ dst,
                              unsigned* __restrict__ rep, int E, int N) {
  int e = blockIdx.x * blockDim.x + threadIdx.x;
  unsigned roff = (unsigned)(blockIdx.x & (R - 1)) * 2u * (unsigned)N;
  if (e < E) {
    atomicAdd(&rep[roff + src[e]], 1u);
    atomicAdd(&rep[roff + (unsigned)N + dst[e]], 1u);
  }
}

__global__ void make_rsqrt_rep(const unsigned* __restrict__ rep,
                               float* __restrict__ rs_out, float* __restrict__ rs_in,
                               unsigned* __restrict__ cnt_in_total, int N) {
  int i = blockIdx.x * blockDim.x + threadIdx.x;
  if (i < N) {
    unsigned vo = 0, vi = 0;
#pragma unroll
    for (int r = 0; r < R; ++r) {
      vo += rep[(size_t)r * 2 * N + i];
      vi += rep[(size_t)r * 2 * N + N + i];
    }
    cnt_in_total[i] = vi;
    float fo = vo ? (float)vo : 1.f;
    float fi = vi ? (float)vi : 1.f;
    rs_out[i] = rsqrtf(fo);
    rs_in[i]  = rsqrtf(fi);
  }
}

// ------------------------------------------------------- 3-phase prefix scan
__global__ void scan_p1(const unsigned* __restrict__ cnt, int n,
                        int* __restrict__ excl, int* __restrict__ bsum) {
  __shared__ int s[256];
  int t = threadIdx.x;
  int i = blockIdx.x * 256 + t;
  int v = (i < n) ? (int)cnt[i] : 0;
  s[t] = v;
  __syncthreads();
  for (int off = 1; off < 256; off <<= 1) {
    int add = (t >= off) ? s[t - off] : 0;
    __syncthreads();
    s[t] += add;
    __syncthreads();
  }
  if (i < n) excl[i] = s[t] - v;
  if (t == 255) bsum[blockIdx.x] = s[255];
}

__global__ void scan_p2(int* bsum, int nb) {
  __shared__ int s[256];
  int t = threadIdx.x;
  int v = (t < nb) ? bsum[t] : 0;
  s[t] = v;
  __syncthreads();
  for (int off = 1; off < 256; off <<= 1) {
    int add = (t >= off) ? s[t - off] : 0;
    __syncthreads();
    s[t] += add;
    __syncthreads();
  }
  if (t < nb) bsum[t] = s[t] - v;
}

__global__ void scan_p3(int* __restrict__ row_ptr, const int* __restrict__ bsum,
                        int n, int E) {
  int i = blockIdx.x * blockDim.x + threadIdx.x;
  if (i < n) row_ptr[i] += bsum[i >> 8];
  if (i == 0) row_ptr[n] = E;
}

// Per-replica cursors: cursor[r][d] = row_ptr[d] + sum_{q<r} cnt_in_q[d]
__global__ void make_cursors(const int* __restrict__ row_ptr,
                             const unsigned* __restrict__ rep,
                             int* __restrict__ cursor, int N) {
  int i = blockIdx.x * blockDim.x + threadIdx.x;
  if (i < N) {
    int base = row_ptr[i];
#pragma unroll
    for (int r = 0; r < R; ++r) {
      cursor[(size_t)r * N + i] = base;
      base += (int)rep[(size_t)r * 2 * N + N + i];
    }
  }
}

// Same grid/block mapping as count_deg_rep => per-replica slot ranges are exact.
__global__ void fill_csr_rep(const int* __restrict__ src, const int* __restrict__ dst,
                             int* cursor, int* __restrict__ csr_src, int E, int N) {
  int e = blockIdx.x * blockDim.x + threadIdx.x;
  if (e < E) {
    int d = dst[e];
    int pos = atomicAdd(&cursor[(size_t)(blockIdx.x & (R - 1)) * N + d], 1);
    csr_src[pos] = src[e];
  }
}

// xp[n] = x[n] * rs_out[n]  (per-row scale), float4-vectorized
__global__ void prescale_rows(const float* __restrict__ x, const float* __restrict__ rs,
                              float* __restrict__ xp, int total4) {
  int i = blockIdx.x * blockDim.x + threadIdx.x;
  if (i < total4) {
    int n = i >> 5;                       // 32 float4 per row
    float r = rs[n];
    float4 v = ((const float4*)x)[i];
    v.x *= r; v.y *= r; v.z *= r; v.w *= r;
    ((float4*)xp)[i] = v;
  }
}

// ------------------------------------------------------------------- SpMM
// One WAVE (64 lanes) per destination node; lane owns a float2 (full 512B row
// per wave instruction). Unroll-by-4 over edges: 4 independent row loads in
// flight. Input rows are pre-scaled by rsqrt(deg_out); output scaled by
// rsqrt(deg_in).
__global__ __launch_bounds__(256) void spmm(const float* __restrict__ X,
    const int* __restrict__ row_ptr, const int* __restrict__ csr_src,
    const float* __restrict__ rs_in, float* __restrict__ out, int N) {
  int n = blockIdx.x * 4 + (threadIdx.x >> 6);
  int lane = threadIdx.x & 63;
  if (n >= N) return;
  int beg = row_ptr[n], end = row_ptr[n + 1];
  float r = rs_in[n];
  const float2* X2 = (const float2*)X;
  float ax = 0.f, ay = 0.f;
  int e = beg;
  for (; e + 4 <= end; e += 4) {
    int s0 = csr_src[e];
    int s1 = csr_src[e + 1];
    int s2 = csr_src[e + 2];
    int s3 = csr_src[e + 3];
    float2 v0 = X2[(size_t)s0 * 64 + lane];
    float2 v1 = X2[(size_t)s1 * 64 + lane];
    float2 v2 = X2[(size_t)s2 * 64 + lane];
    float2 v3 = X2[(size_t)s3 * 64 + lane];
    ax += (v0.x + v1.x) + (v2.x + v3.x);
    ay += (v0.y + v1.y) + (v2.y + v3.y);
  }
  for (; e < end; ++e) {
    int s = csr_src[e];
    float2 v = X2[(size_t)s * 64 + lane];
    ax += v.x;
    ay += v.y;
  }
  float2 o;
  o.x = ax * r;
  o.y = ay * r;
  ((float2*)out)[(size_t)n * 64 + lane] = o;
}

// ------------------------------------------------------------------- GEMM
// C[nrows x 128] = relu(M @ W + b) * postscale (optional, per row).
// Block: 256 threads = 16x16; thread computes 4 rows x 8 cols. W in LDS.
// Safe in-place (out == M): block touches only its own 64 rows; sync before store.
__global__ __launch_bounds__(256) void gemm_bias_relu(
    const float* __restrict__ M, const float* __restrict__ W,
    const float* __restrict__ bias, const float* __restrict__ postscale,
    float* __restrict__ out, int nrows) {
  __shared__ float Wl[D * D];  // 64 KB
  int t = threadIdx.x;
  {
    const float4* W4 = (const float4*)W;
    float4* Wl4 = (float4*)Wl;
#pragma unroll
    for (int i = 0; i < 16; ++i) Wl4[t + i * 256] = W4[t + i * 256];
  }
  __syncthreads();

  int tx = t & 15;   // col group: 8 cols
  int ty = t >> 4;   // row group: 4 rows
  int rbase = blockIdx.x * 64 + ty * 4;
  int c0 = tx * 8;

  float acc[4][8];
#pragma unroll
  for (int i = 0; i < 4; ++i)
#pragma unroll
    for (int c = 0; c < 8; ++c) acc[i][c] = 0.f;

  int r[4];
#pragma unroll
  for (int i = 0; i < 4; ++i) {
    r[i] = rbase + i;
    if (r[i] > nrows - 1) r[i] = nrows - 1;  // clamp; discarded at store
  }

  const float4* M4 = (const float4*)M;
  for (int k4 = 0; k4 < D / 4; ++k4) {
    float4 mv[4];
#pragma unroll
    for (int i = 0; i < 4; ++i) mv[i] = M4[r[i] * (D / 4) + k4];
    float mk[4][4];
#pragma unroll
    for (int i = 0; i < 4; ++i) {
      mk[i][0] = mv[i].x; mk[i][1] = mv[i].y; mk[i][2] = mv[i].z; mk[i][3] = mv[i].w;
    }
#pragma unroll
    for (int kk = 0; kk < 4; ++kk) {
      const float* wrow = Wl + (k4 * 4 + kk) * D + c0;
      float4 w0 = *(const float4*)(wrow);
      float4 w1 = *(const float4*)(wrow + 4);
      float wv[8] = {w0.x, w0.y, w0.z, w0.w, w1.x, w1.y, w1.z, w1.w};
#pragma unroll
      for (int i = 0; i < 4; ++i)
#pragma unroll
        for (int c = 0; c < 8; ++c) acc[i][c] += mk[i][kk] * wv[c];
    }
  }

  __syncthreads();  // all in-place reads of M complete before writes

#pragma unroll
  for (int i = 0; i < 4; ++i) {
    int rr = rbase + i;
    if (rr < nrows) {
      float ps = postscale ? postscale[rr] : 1.f;
      float4 o0, o1;
      o0.x = fmaxf(acc[i][0] + bias[c0 + 0], 0.f) * ps;
      o0.y = fmaxf(acc[i][1] + bias[c0 + 1], 0.f) * ps;
      o0.z = fmaxf(acc[i][2] + bias[c0 + 2], 0.f) * ps;
      o0.w = fmaxf(acc[i][3] + bias[c0 + 3], 0.f) * ps;
      o1.x = fmaxf(acc[i][4] + bias[c0 + 4], 0.f) * ps;
      o1.y = fmaxf(acc[i][5] + bias[c0 + 5], 0.f) * ps;
      o1.z = fmaxf(acc[i][6] + bias[c0 + 6], 0.f) * ps;
      o1.w = fmaxf(acc[i][7] + bias[c0 + 7], 0.f) * ps;
      *(float4*)(out + rr * D + c0)     = o0;
      *(float4*)(out + rr * D + c0 + 4) = o1;
    }
  }
}

// ------------------------------------------------------------------- score
// One wave (64 lanes) per score edge; lane handles features {lane, lane+64}.
__global__ void score_kernel(const float* __restrict__ H, const int* __restrict__ ss,
                             const int* __restrict__ sd, float* __restrict__ out, int ES) {
  int wid = (int)((blockIdx.x * blockDim.x + threadIdx.x) >> 6);
  int lane = threadIdx.x & 63;
  if (wid >= ES) return;
  int a = ss[wid], b = sd[wid];
  const float* pa = H + (size_t)a * D;
  const float* pb = H + (size_t)b * D;
  float p = pa[lane] * pb[lane] + pa[lane + 64] * pb[lane + 64];
#pragma unroll
  for (int off = 32; off > 0; off >>= 1) p += __shfl_xor(p, off, 64);
  if (lane == 0) out[wid] = p;
}

// ------------------------------------------------------------------ launch
extern "C" void kernel_launch(void* const* d_in, const int* in_sizes, int n_in,
                              void* d_out, int out_size, void* d_ws, size_t ws_size,
                              hipStream_t stream) {
  const float* x   = (const float*)d_in[0];
  const int* esrc  = (const int*)d_in[1];
  const int* edst  = (const int*)d_in[2];
  const int* ssrc  = (const int*)d_in[3];
  const int* sdst  = (const int*)d_in[4];
  const float* W1  = (const float*)d_in[5];
  const float* b1  = (const float*)d_in[6];
  const float* W2  = (const float*)d_in[7];
  const float* b2  = (const float*)d_in[8];
  float* out = (float*)d_out;

  const int N  = in_sizes[0] / D;  // 50000
  const int E  = in_sizes[1];      // 800000
  const int ES = in_sizes[3];      // 200000

  char* w = (char*)d_ws;
  auto take = [&](size_t bytes) {
    char* p = w;
    w += (bytes + 255) & ~(size_t)255;
    return p;
  };
  float* rs_out = (float*)take((size_t)N * 4);
  float* rs_in  = (float*)take((size_t)N * 4);
  unsigned* cnt_in_total = (unsigned*)take((size_t)N * 4);
  int* row_ptr  = (int*)take((size_t)(N + 1) * 4);
  int* bsum     = (int*)take(256 * 4);
  int* csr_src  = (int*)take((size_t)E * 4);
  float* bufA   = (float*)take((size_t)N * D * 4);
  float* bufB   = (float*)take((size_t)N * D * 4);

  // rep (R*2N u32 = 3.2 MB) and cursor (R*N = 1.6 MB) alias into bufA:
  // both are fully consumed (make_rsqrt/make_cursors/fill_csr) before the
  // first spmm writes bufA.
  unsigned* rep = (unsigned*)bufA;
  int* cursor   = (int*)(bufA + (size_t)2 * N * R);

  int nb  = (N + 255) / 256;
  int ngE = (E + 255) / 256;

  zero_u32<<<2048, 256, 0, stream>>>(rep, 2 * N * R);
  count_deg_rep<<<ngE, 256, 0, stream>>>(esrc, edst, rep, E, N);
  make_rsqrt_rep<<<nb, 256, 0, stream>>>(rep, rs_out, rs_in, cnt_in_total, N);
  scan_p1<<<nb, 256, 0, stream>>>(cnt_in_total, N, row_ptr, bsum);
  scan_p2<<<1, 256, 0, stream>>>(bsum, nb);
  scan_p3<<<nb, 256, 0, stream>>>(row_ptr, bsum, N, E);
  make_cursors<<<nb, 256, 0, stream>>>(row_ptr, rep, cursor, N);
  fill_csr_rep<<<ngE, 256, 0, stream>>>(esrc, edst, cursor, csr_src, E, N);

  // Prescale x by rsqrt(deg_out) into bufB (free until layer-2 SpMM writes it).
  prescale_rows<<<(N * 32 + 255) / 256, 256, 0, stream>>>(x, rs_out, bufB, N * 32);

  // Layer 1: SpMM(x_prescaled) -> bufA; GEMM in-place, epilogue pre-scales
  // by rs_out so h1 is ready for layer-2 gather.
  spmm<<<(N + 3) / 4, 256, 0, stream>>>(bufB, row_ptr, csr_src, rs_in, bufA, N);
  gemm_bias_relu<<<(N + 63) / 64, 256, 0, stream>>>(bufA, W1, b1, rs_out, bufA, N);

  // Layer 2: SpMM(h1_prescaled) -> bufB; GEMM in-place, no post-scale.
  spmm<<<(N + 3) / 4, 256, 0, stream>>>(bufA, row_ptr, csr_src, rs_in, bufB, N);
  gemm_bias_relu<<<(N + 63) / 64, 256, 0, stream>>>(bufB, W2, b2, nullptr, bufB, N);

  score_kernel<<<(ES + 3) / 4, 256, 0, stream>>>(bufB, ssrc, sdst, out, ES);
}

// Round 11
// 382.599 us; speedup vs baseline: 1.1282x; 1.1282x over previous
//
#include <hip/hip_runtime.h>

#define D 128
#define NBLK_BIN 64   // blocks for binning phases (A, C)
#define MAXBUCK 1024  // LDS histogram capacity; NBUCK = ceil(N/64) = 782

// ---------------------------------------------------------------- utilities
__global__ void zero_u32(unsigned* p, int n) {
  int i = blockIdx.x * blockDim.x + threadIdx.x;
  int stride = gridDim.x * blockDim.x;
  for (; i < n; i += stride) p[i] = 0u;
}

// ---------------- Phase A: per-block LDS bucket histograms (dst & src), flush
__global__ __launch_bounds__(256) void phaseA(const int* __restrict__ src,
    const int* __restrict__ dst, unsigned* __restrict__ gcnt_dst,
    unsigned* __restrict__ gcnt_src, int E, int NBUCK, int chunk) {
  __shared__ unsigned hd[MAXBUCK], hs[MAXBUCK];
  int t = threadIdx.x;
  for (int j = t; j < NBUCK; j += 256) { hd[j] = 0u; hs[j] = 0u; }
  __syncthreads();
  int beg = blockIdx.x * chunk, end = min(E, beg + chunk);
  for (int i = beg + t; i < end; i += 256) {
    atomicAdd(&hd[dst[i] >> 6], 1u);
    atomicAdd(&hs[src[i] >> 6], 1u);
  }
  __syncthreads();
  for (int j = t; j < NBUCK; j += 256) {
    if (hd[j]) atomicAdd(&gcnt_dst[j], hd[j]);
    if (hs[j]) atomicAdd(&gcnt_src[j], hs[j]);
  }
}

// ---------------- Phase B: exclusive scan of bucket counts -> bases & cursors
__global__ __launch_bounds__(1024) void phaseB(const unsigned* __restrict__ gcnt_dst,
    const unsigned* __restrict__ gcnt_src, int* __restrict__ base_dst,
    int* __restrict__ base_src, int* __restrict__ gcur_dst,
    int* __restrict__ gcur_src, int* __restrict__ row_ptr,
    int N, int E, int NBUCK) {
  __shared__ int s[1024];
  int t = threadIdx.x;
  int v = (t < NBUCK) ? (int)gcnt_dst[t] : 0;
  s[t] = v;
  __syncthreads();
  for (int off = 1; off < 1024; off <<= 1) {
    int a = (t >= off) ? s[t - off] : 0;
    __syncthreads(); s[t] += a; __syncthreads();
  }
  if (t < NBUCK) { int e = s[t] - v; base_dst[t] = e; gcur_dst[t] = e; }
  if (t == 0) { base_dst[NBUCK] = E; row_ptr[N] = E; }
  __syncthreads();
  v = (t < NBUCK) ? (int)gcnt_src[t] : 0;
  s[t] = v;
  __syncthreads();
  for (int off = 1; off < 1024; off <<= 1) {
    int a = (t >= off) ? s[t - off] : 0;
    __syncthreads(); s[t] += a; __syncthreads();
  }
  if (t < NBUCK) { int e = s[t] - v; base_src[t] = e; gcur_src[t] = e; }
  if (t == 0) base_src[NBUCK] = E;
}

// ---------------- Phase C: bulk-reserve per (block,bucket), scatter to buckets
__global__ __launch_bounds__(256) void phaseC(const int* __restrict__ src,
    const int* __restrict__ dst, int* gcur_dst, int* gcur_src,
    unsigned long long* __restrict__ bkt, int* __restrict__ bkt_src,
    int E, int NBUCK, int chunk) {
  __shared__ int hd[MAXBUCK], hs[MAXBUCK];
  int t = threadIdx.x;
  for (int j = t; j < NBUCK; j += 256) { hd[j] = 0; hs[j] = 0; }
  __syncthreads();
  int beg = blockIdx.x * chunk, end = min(E, beg + chunk);
  for (int i = beg + t; i < end; i += 256) {
    atomicAdd(&hd[dst[i] >> 6], 1);
    atomicAdd(&hs[src[i] >> 6], 1);
  }
  __syncthreads();
  // reserve: hd[j]/hs[j] become this block's running global cursors
  for (int j = t; j < NBUCK; j += 256) {
    int c = hd[j]; if (c) hd[j] = atomicAdd(&gcur_dst[j], c);
    c = hs[j];     if (c) hs[j] = atomicAdd(&gcur_src[j], c);
  }
  __syncthreads();
  for (int i = beg + t; i < end; i += 256) {
    int d = dst[i], s2 = src[i];
    int p = atomicAdd(&hd[d >> 6], 1);
    bkt[p] = ((unsigned long long)(unsigned)s2 << 32) | (unsigned)d;
    int q = atomicAdd(&hs[s2 >> 6], 1);
    bkt_src[q] = s2;
  }
}

// ---------------- Phase D (dst): per-bucket 64-node histogram -> row_ptr,
// rs_in, and in-bucket scatter of csr_src. One block per bucket.
__global__ __launch_bounds__(256) void phaseD_dst(
    const unsigned long long* __restrict__ bkt, const int* __restrict__ base_dst,
    int* __restrict__ row_ptr, float* __restrict__ rs_in,
    int* __restrict__ csr_src, int N) {
  __shared__ int hist[64], excl[65], cur[64];
  int b = blockIdx.x, t = threadIdx.x;
  int beg = base_dst[b], end = base_dst[b + 1];
  if (t < 64) hist[t] = 0;
  __syncthreads();
  for (int i = beg + t; i < end; i += 256)
    atomicAdd(&hist[(int)(bkt[i] & 0xffffffffu) & 63], 1);
  __syncthreads();
  if (t == 0) {
    int acc = 0;
    for (int j = 0; j < 64; ++j) { excl[j] = acc; acc += hist[j]; }
    excl[64] = acc;
  }
  __syncthreads();
  if (t < 64) {
    cur[t] = excl[t];
    int v = b * 64 + t;
    if (v < N) {
      row_ptr[v] = beg + excl[t];
      rs_in[v] = rsqrtf((float)(hist[t] > 0 ? hist[t] : 1));
    }
  }
  __syncthreads();
  for (int i = beg + t; i < end; i += 256) {
    unsigned long long p = bkt[i];
    int d = (int)(p & 0xffffffffu);
    int pos = atomicAdd(&cur[d & 63], 1);
    csr_src[beg + pos] = (int)(p >> 32);
  }
}

// ---------------- Phase D (src): per-bucket histogram -> rs_out
__global__ __launch_bounds__(256) void phaseD_src(
    const int* __restrict__ bkt_src, const int* __restrict__ base_src,
    float* __restrict__ rs_out, int N) {
  __shared__ int hist[64];
  int b = blockIdx.x, t = threadIdx.x;
  int beg = base_src[b], end = base_src[b + 1];
  if (t < 64) hist[t] = 0;
  __syncthreads();
  for (int i = beg + t; i < end; i += 256)
    atomicAdd(&hist[bkt_src[i] & 63], 1);
  __syncthreads();
  if (t < 64) {
    int v = b * 64 + t;
    if (v < N) rs_out[v] = rsqrtf((float)(hist[t] > 0 ? hist[t] : 1));
  }
}

// xp[n] = x[n] * rs_out[n]  (per-row scale), float4-vectorized
__global__ void prescale_rows(const float* __restrict__ x, const float* __restrict__ rs,
                              float* __restrict__ xp, int total4) {
  int i = blockIdx.x * blockDim.x + threadIdx.x;
  if (i < total4) {
    int n = i >> 5;                       // 32 float4 per row
    float r = rs[n];
    float4 v = ((const float4*)x)[i];
    v.x *= r; v.y *= r; v.z *= r; v.w *= r;
    ((float4*)xp)[i] = v;
  }
}

// ------------------------------------------------------------------- SpMM
// One WAVE (64 lanes) per destination node; lane owns a float2 (full 512B row
// per wave instruction). Unroll-by-4 over edges: 4 independent row loads in
// flight. Input rows are pre-scaled by rsqrt(deg_out); output scaled by
// rsqrt(deg_in).
__global__ __launch_bounds__(256) void spmm(const float* __restrict__ X,
    const int* __restrict__ row_ptr, const int* __restrict__ csr_src,
    const float* __restrict__ rs_in, float* __restrict__ out, int N) {
  int n = blockIdx.x * 4 + (threadIdx.x >> 6);
  int lane = threadIdx.x & 63;
  if (n >= N) return;
  int beg = row_ptr[n], end = row_ptr[n + 1];
  float r = rs_in[n];
  const float2* X2 = (const float2*)X;
  float ax = 0.f, ay = 0.f;
  int e = beg;
  for (; e + 4 <= end; e += 4) {
    int s0 = csr_src[e];
    int s1 = csr_src[e + 1];
    int s2 = csr_src[e + 2];
    int s3 = csr_src[e + 3];
    float2 v0 = X2[(size_t)s0 * 64 + lane];
    float2 v1 = X2[(size_t)s1 * 64 + lane];
    float2 v2 = X2[(size_t)s2 * 64 + lane];
    float2 v3 = X2[(size_t)s3 * 64 + lane];
    ax += (v0.x + v1.x) + (v2.x + v3.x);
    ay += (v0.y + v1.y) + (v2.y + v3.y);
  }
  for (; e < end; ++e) {
    int s = csr_src[e];
    float2 v = X2[(size_t)s * 64 + lane];
    ax += v.x;
    ay += v.y;
  }
  float2 o;
  o.x = ax * r;
  o.y = ay * r;
  ((float2*)out)[(size_t)n * 64 + lane] = o;
}

// ------------------------------------------------------------------- GEMM
// C[nrows x 128] = relu(M @ W + b) * postscale (optional, per row).
// Block: 256 threads = 16x16; thread computes 4 rows x 8 cols. W in LDS.
// Safe in-place (out == M): block touches only its own 64 rows; sync before store.
__global__ __launch_bounds__(256) void gemm_bias_relu(
    const float* __restrict__ M, const float* __restrict__ W,
    const float* __restrict__ bias, const float* __restrict__ postscale,
    float* __restrict__ out, int nrows) {
  __shared__ float Wl[D * D];  // 64 KB
  int t = threadIdx.x;
  {
    const float4* W4 = (const float4*)W;
    float4* Wl4 = (float4*)Wl;
#pragma unroll
    for (int i = 0; i < 16; ++i) Wl4[t + i * 256] = W4[t + i * 256];
  }
  __syncthreads();

  int tx = t & 15;   // col group: 8 cols
  int ty = t >> 4;   // row group: 4 rows
  int rbase = blockIdx.x * 64 + ty * 4;
  int c0 = tx * 8;

  float acc[4][8];
#pragma unroll
  for (int i = 0; i < 4; ++i)
#pragma unroll
    for (int c = 0; c < 8; ++c) acc[i][c] = 0.f;

  int r[4];
#pragma unroll
  for (int i = 0; i < 4; ++i) {
    r[i] = rbase + i;
    if (r[i] > nrows - 1) r[i] = nrows - 1;  // clamp; discarded at store
  }

  const float4* M4 = (const float4*)M;
  for (int k4 = 0; k4 < D / 4; ++k4) {
    float4 mv[4];
#pragma unroll
    for (int i = 0; i < 4; ++i) mv[i] = M4[r[i] * (D / 4) + k4];
    float mk[4][4];
#pragma unroll
    for (int i = 0; i < 4; ++i) {
      mk[i][0] = mv[i].x; mk[i][1] = mv[i].y; mk[i][2] = mv[i].z; mk[i][3] = mv[i].w;
    }
#pragma unroll
    for (int kk = 0; kk < 4; ++kk) {
      const float* wrow = Wl + (k4 * 4 + kk) * D + c0;
      float4 w0 = *(const float4*)(wrow);
      float4 w1 = *(const float4*)(wrow + 4);
      float wv[8] = {w0.x, w0.y, w0.z, w0.w, w1.x, w1.y, w1.z, w1.w};
#pragma unroll
      for (int i = 0; i < 4; ++i)
#pragma unroll
        for (int c = 0; c < 8; ++c) acc[i][c] += mk[i][kk] * wv[c];
    }
  }

  __syncthreads();  // all in-place reads of M complete before writes

#pragma unroll
  for (int i = 0; i < 4; ++i) {
    int rr = rbase + i;
    if (rr < nrows) {
      float ps = postscale ? postscale[rr] : 1.f;
      float4 o0, o1;
      o0.x = fmaxf(acc[i][0] + bias[c0 + 0], 0.f) * ps;
      o0.y = fmaxf(acc[i][1] + bias[c0 + 1], 0.f) * ps;
      o0.z = fmaxf(acc[i][2] + bias[c0 + 2], 0.f) * ps;
      o0.w = fmaxf(acc[i][3] + bias[c0 + 3], 0.f) * ps;
      o1.x = fmaxf(acc[i][4] + bias[c0 + 4], 0.f) * ps;
      o1.y = fmaxf(acc[i][5] + bias[c0 + 5], 0.f) * ps;
      o1.z = fmaxf(acc[i][6] + bias[c0 + 6], 0.f) * ps;
      o1.w = fmaxf(acc[i][7] + bias[c0 + 7], 0.f) * ps;
      *(float4*)(out + rr * D + c0)     = o0;
      *(float4*)(out + rr * D + c0 + 4) = o1;
    }
  }
}

// ------------------------------------------------------------------- score
// One wave (64 lanes) per score edge; lane handles features {lane, lane+64}.
__global__ void score_kernel(const float* __restrict__ H, const int* __restrict__ ss,
                             const int* __restrict__ sd, float* __restrict__ out, int ES) {
  int wid = (int)((blockIdx.x * blockDim.x + threadIdx.x) >> 6);
  int lane = threadIdx.x & 63;
  if (wid >= ES) return;
  int a = ss[wid], b = sd[wid];
  const float* pa = H + (size_t)a * D;
  const float* pb = H + (size_t)b * D;
  float p = pa[lane] * pb[lane] + pa[lane + 64] * pb[lane + 64];
#pragma unroll
  for (int off = 32; off > 0; off >>= 1) p += __shfl_xor(p, off, 64);
  if (lane == 0) out[wid] = p;
}

// ------------------------------------------------------------------ launch
extern "C" void kernel_launch(void* const* d_in, const int* in_sizes, int n_in,
                              void* d_out, int out_size, void* d_ws, size_t ws_size,
                              hipStream_t stream) {
  const float* x   = (const float*)d_in[0];
  const int* esrc  = (const int*)d_in[1];
  const int* edst  = (const int*)d_in[2];
  const int* ssrc  = (const int*)d_in[3];
  const int* sdst  = (const int*)d_in[4];
  const float* W1  = (const float*)d_in[5];
  const float* b1  = (const float*)d_in[6];
  const float* W2  = (const float*)d_in[7];
  const float* b2  = (const float*)d_in[8];
  float* out = (float*)d_out;

  const int N  = in_sizes[0] / D;  // 50000
  const int E  = in_sizes[1];      // 800000
  const int ES = in_sizes[3];      // 200000
  const int NBUCK = (N + 63) >> 6; // 782

  char* w = (char*)d_ws;
  auto take = [&](size_t bytes) {
    char* p = w;
    w += (bytes + 255) & ~(size_t)255;
    return p;
  };
  float* rs_out = (float*)take((size_t)N * 4);
  float* rs_in  = (float*)take((size_t)N * 4);
  int* row_ptr  = (int*)take((size_t)(N + 1) * 4);
  unsigned* gcnt = (unsigned*)take((size_t)2 * MAXBUCK * 4);
  int* base_dst = (int*)take((size_t)(MAXBUCK + 1) * 4);
  int* base_src = (int*)take((size_t)(MAXBUCK + 1) * 4);
  int* gcur_dst = (int*)take((size_t)MAXBUCK * 4);
  int* gcur_src = (int*)take((size_t)MAXBUCK * 4);
  int* csr_src  = (int*)take((size_t)E * 4);
  float* bufA   = (float*)take((size_t)N * D * 4);
  float* bufB   = (float*)take((size_t)N * D * 4);

  unsigned* gcnt_dst = gcnt;
  unsigned* gcnt_src = gcnt + MAXBUCK;
  // bucket arrays (E*8 + E*4 = 9.6 MB) alias into bufA (25.6 MB): fully
  // consumed by phaseD_* before the first spmm writes bufA.
  unsigned long long* bkt = (unsigned long long*)bufA;
  int* bkt_src = (int*)(bufA + (size_t)E * 2);  // E*2 floats = E*8 bytes

  const int chunk = (E + NBLK_BIN - 1) / NBLK_BIN;

  // ---- CSR + degrees via two-level LDS-aggregated counting sort
  zero_u32<<<8, 256, 0, stream>>>(gcnt, 2 * MAXBUCK);
  phaseA<<<NBLK_BIN, 256, 0, stream>>>(esrc, edst, gcnt_dst, gcnt_src, E, NBUCK, chunk);
  phaseB<<<1, 1024, 0, stream>>>(gcnt_dst, gcnt_src, base_dst, base_src,
                                 gcur_dst, gcur_src, row_ptr, N, E, NBUCK);
  phaseC<<<NBLK_BIN, 256, 0, stream>>>(esrc, edst, gcur_dst, gcur_src,
                                       bkt, bkt_src, E, NBUCK, chunk);
  phaseD_dst<<<NBUCK, 256, 0, stream>>>(bkt, base_dst, row_ptr, rs_in, csr_src, N);
  phaseD_src<<<NBUCK, 256, 0, stream>>>(bkt_src, base_src, rs_out, N);

  // Prescale x by rsqrt(deg_out) into bufB (free until layer-2 SpMM writes it).
  prescale_rows<<<(N * 32 + 255) / 256, 256, 0, stream>>>(x, rs_out, bufB, N * 32);

  // Layer 1: SpMM(x_prescaled) -> bufA; GEMM in-place, epilogue pre-scales
  // by rs_out so h1 is ready for layer-2 gather.
  spmm<<<(N + 3) / 4, 256, 0, stream>>>(bufB, row_ptr, csr_src, rs_in, bufA, N);
  gemm_bias_relu<<<(N + 63) / 64, 256, 0, stream>>>(bufA, W1, b1, rs_out, bufA, N);

  // Layer 2: SpMM(h1_prescaled) -> bufB; GEMM in-place, no post-scale.
  spmm<<<(N + 3) / 4, 256, 0, stream>>>(bufA, row_ptr, csr_src, rs_in, bufB, N);
  gemm_bias_relu<<<(N + 63) / 64, 256, 0, stream>>>(bufB, W2, b2, nullptr, bufB, N);

  score_kernel<<<(ES + 3) / 4, 256, 0, stream>>>(bufB, ssrc, sdst, out, ES);
}

// Round 14
// 381.655 us; speedup vs baseline: 1.1310x; 1.0025x over previous
//
#include <hip/hip_runtime.h>

#define D 128
#define NBLK_BIN 64   // blocks for binning phases (A, C)
#define MAXBUCK 1024  // LDS histogram capacity; NBUCK = ceil(N/64) = 782

// ---------------------------------------------------------------- utilities
__global__ void zero_u32(unsigned* p, int n) {
  int i = blockIdx.x * blockDim.x + threadIdx.x;
  int stride = gridDim.x * blockDim.x;
  for (; i < n; i += stride) p[i] = 0u;
}

// ---------------- Phase A: per-block LDS bucket histograms (dst & src), flush
__global__ __launch_bounds__(256) void phaseA(const int* __restrict__ src,
    const int* __restrict__ dst, unsigned* __restrict__ gcnt_dst,
    unsigned* __restrict__ gcnt_src, int E, int NBUCK, int chunk) {
  __shared__ unsigned hd[MAXBUCK], hs[MAXBUCK];
  int t = threadIdx.x;
  for (int j = t; j < NBUCK; j += 256) { hd[j] = 0u; hs[j] = 0u; }
  __syncthreads();
  int beg = blockIdx.x * chunk, end = min(E, beg + chunk);
  for (int i = beg + t; i < end; i += 256) {
    atomicAdd(&hd[dst[i] >> 6], 1u);
    atomicAdd(&hs[src[i] >> 6], 1u);
  }
  __syncthreads();
  for (int j = t; j < NBUCK; j += 256) {
    if (hd[j]) atomicAdd(&gcnt_dst[j], hd[j]);
    if (hs[j]) atomicAdd(&gcnt_src[j], hs[j]);
  }
}

// ---------------- Phase B: exclusive scan of bucket counts -> bases & cursors
__global__ __launch_bounds__(1024) void phaseB(const unsigned* __restrict__ gcnt_dst,
    const unsigned* __restrict__ gcnt_src, int* __restrict__ base_dst,
    int* __restrict__ base_src, int* __restrict__ gcur_dst,
    int* __restrict__ gcur_src, int* __restrict__ row_ptr,
    int N, int E, int NBUCK) {
  __shared__ int s[1024];
  int t = threadIdx.x;
  int v = (t < NBUCK) ? (int)gcnt_dst[t] : 0;
  s[t] = v;
  __syncthreads();
  for (int off = 1; off < 1024; off <<= 1) {
    int a = (t >= off) ? s[t - off] : 0;
    __syncthreads(); s[t] += a; __syncthreads();
  }
  if (t < NBUCK) { int e = s[t] - v; base_dst[t] = e; gcur_dst[t] = e; }
  if (t == 0) { base_dst[NBUCK] = E; row_ptr[N] = E; }
  __syncthreads();
  v = (t < NBUCK) ? (int)gcnt_src[t] : 0;
  s[t] = v;
  __syncthreads();
  for (int off = 1; off < 1024; off <<= 1) {
    int a = (t >= off) ? s[t - off] : 0;
    __syncthreads(); s[t] += a; __syncthreads();
  }
  if (t < NBUCK) { int e = s[t] - v; base_src[t] = e; gcur_src[t] = e; }
  if (t == 0) base_src[NBUCK] = E;
}

// ---------------- Phase C: bulk-reserve per (block,bucket), scatter to buckets
__global__ __launch_bounds__(256) void phaseC(const int* __restrict__ src,
    const int* __restrict__ dst, int* gcur_dst, int* gcur_src,
    unsigned long long* __restrict__ bkt, int* __restrict__ bkt_src,
    int E, int NBUCK, int chunk) {
  __shared__ int hd[MAXBUCK], hs[MAXBUCK];
  int t = threadIdx.x;
  for (int j = t; j < NBUCK; j += 256) { hd[j] = 0; hs[j] = 0; }
  __syncthreads();
  int beg = blockIdx.x * chunk, end = min(E, beg + chunk);
  for (int i = beg + t; i < end; i += 256) {
    atomicAdd(&hd[dst[i] >> 6], 1);
    atomicAdd(&hs[src[i] >> 6], 1);
  }
  __syncthreads();
  // reserve: hd[j]/hs[j] become this block's running global cursors
  for (int j = t; j < NBUCK; j += 256) {
    int c = hd[j]; if (c) hd[j] = atomicAdd(&gcur_dst[j], c);
    c = hs[j];     if (c) hs[j] = atomicAdd(&gcur_src[j], c);
  }
  __syncthreads();
  for (int i = beg + t; i < end; i += 256) {
    int d = dst[i], s2 = src[i];
    int p = atomicAdd(&hd[d >> 6], 1);
    bkt[p] = ((unsigned long long)(unsigned)s2 << 32) | (unsigned)d;
    int q = atomicAdd(&hs[s2 >> 6], 1);
    bkt_src[q] = s2;
  }
}

// ---------------- Phase D (fused): per-bucket dst histogram -> row_ptr, rs_in,
// csr_src scatter; src histogram -> rs_out; then prescale this bucket's 64
// rows of x by rs_out into xp. One block per bucket.
__global__ __launch_bounds__(256) void phaseD(
    const unsigned long long* __restrict__ bkt, const int* __restrict__ base_dst,
    const int* __restrict__ bkt_src, const int* __restrict__ base_src,
    int* __restrict__ row_ptr, float* __restrict__ rs_in,
    float* __restrict__ rs_out, int* __restrict__ csr_src,
    const float* __restrict__ x, float* __restrict__ xp, int N) {
  __shared__ int hist[64], excl[65], cur[64], hist2[64];
  __shared__ float rsv[64];
  int b = blockIdx.x, t = threadIdx.x;

  // ---- dst side
  int beg = base_dst[b], end = base_dst[b + 1];
  if (t < 64) { hist[t] = 0; hist2[t] = 0; }
  __syncthreads();
  for (int i = beg + t; i < end; i += 256)
    atomicAdd(&hist[(int)(bkt[i] & 0xffffffffu) & 63], 1);
  __syncthreads();
  if (t == 0) {
    int acc = 0;
    for (int j = 0; j < 64; ++j) { excl[j] = acc; acc += hist[j]; }
    excl[64] = acc;
  }
  __syncthreads();
  if (t < 64) {
    cur[t] = excl[t];
    int v = b * 64 + t;
    if (v < N) {
      row_ptr[v] = beg + excl[t];
      rs_in[v] = rsqrtf((float)(hist[t] > 0 ? hist[t] : 1));
    }
  }
  __syncthreads();
  for (int i = beg + t; i < end; i += 256) {
    unsigned long long p = bkt[i];
    int d = (int)(p & 0xffffffffu);
    int pos = atomicAdd(&cur[d & 63], 1);
    csr_src[beg + pos] = (int)(p >> 32);
  }

  // ---- src side -> rs_out (+ LDS copy for prescale)
  int beg2 = base_src[b], end2 = base_src[b + 1];
  for (int i = beg2 + t; i < end2; i += 256)
    atomicAdd(&hist2[bkt_src[i] & 63], 1);
  __syncthreads();
  if (t < 64) {
    float r = rsqrtf((float)(hist2[t] > 0 ? hist2[t] : 1));
    rsv[t] = r;
    int v = b * 64 + t;
    if (v < N) rs_out[v] = r;
  }
  __syncthreads();

  // ---- prescale rows [b*64, b*64+64) of x into xp (float4, 8 per thread)
  const float4* x4 = (const float4*)x;
  float4* xp4 = (float4*)xp;
#pragma unroll
  for (int j = 0; j < 8; ++j) {
    int idx = j * 256 + t;          // 0..2047 over 64 rows x 32 float4
    int row = idx >> 5;
    int node = b * 64 + row;
    if (node < N) {
      float r = rsv[row];
      float4 v = x4[(size_t)node * 32 + (idx & 31)];
      v.x *= r; v.y *= r; v.z *= r; v.w *= r;
      xp4[(size_t)node * 32 + (idx & 31)] = v;
    }
  }
}

// ------------------------------------------------------------------- SpMM
// One WAVE (64 lanes) per destination node; lane owns a float2 (full 512B row
// per wave instruction). Unroll-by-8 over edges: 8 independent row loads
// (4 KB) in flight per wave to hide HBM/L2-miss latency.
__global__ __launch_bounds__(256) void spmm(const float* __restrict__ X,
    const int* __restrict__ row_ptr, const int* __restrict__ csr_src,
    const float* __restrict__ rs_in, float* __restrict__ out, int N) {
  int n = blockIdx.x * 4 + (threadIdx.x >> 6);
  int lane = threadIdx.x & 63;
  if (n >= N) return;
  int beg = row_ptr[n], end = row_ptr[n + 1];
  float r = rs_in[n];
  const float2* X2 = (const float2*)X;
  float ax = 0.f, ay = 0.f;
  int e = beg;
  for (; e + 8 <= end; e += 8) {
    int idx[8];
#pragma unroll
    for (int k = 0; k < 8; ++k) idx[k] = csr_src[e + k];
    float2 v[8];
#pragma unroll
    for (int k = 0; k < 8; ++k) v[k] = X2[(size_t)idx[k] * 64 + lane];
#pragma unroll
    for (int k = 0; k < 8; ++k) { ax += v[k].x; ay += v[k].y; }
  }
  if (e + 4 <= end) {
    int i0 = csr_src[e], i1 = csr_src[e + 1], i2 = csr_src[e + 2], i3 = csr_src[e + 3];
    float2 v0 = X2[(size_t)i0 * 64 + lane];
    float2 v1 = X2[(size_t)i1 * 64 + lane];
    float2 v2 = X2[(size_t)i2 * 64 + lane];
    float2 v3 = X2[(size_t)i3 * 64 + lane];
    ax += (v0.x + v1.x) + (v2.x + v3.x);
    ay += (v0.y + v1.y) + (v2.y + v3.y);
    e += 4;
  }
  for (; e < end; ++e) {
    int s = csr_src[e];
    float2 v = X2[(size_t)s * 64 + lane];
    ax += v.x;
    ay += v.y;
  }
  float2 o;
  o.x = ax * r;
  o.y = ay * r;
  ((float2*)out)[(size_t)n * 64 + lane] = o;
}

// ------------------------------------------------------------------- GEMM
// C[nrows x 128] = relu(M @ W + b) * postscale (optional, per row).
// Block: 256 threads = 16x16; thread computes 4 rows x 8 cols. W in LDS.
// Safe in-place (out == M): block touches only its own 64 rows; sync before store.
__global__ __launch_bounds__(256) void gemm_bias_relu(
    const float* __restrict__ M, const float* __restrict__ W,
    const float* __restrict__ bias, const float* __restrict__ postscale,
    float* __restrict__ out, int nrows) {
  __shared__ float Wl[D * D];  // 64 KB
  int t = threadIdx.x;
  {
    const float4* W4 = (const float4*)W;
    float4* Wl4 = (float4*)Wl;
#pragma unroll
    for (int i = 0; i < 16; ++i) Wl4[t + i * 256] = W4[t + i * 256];
  }
  __syncthreads();

  int tx = t & 15;   // col group: 8 cols
  int ty = t >> 4;   // row group: 4 rows
  int rbase = blockIdx.x * 64 + ty * 4;
  int c0 = tx * 8;

  float acc[4][8];
#pragma unroll
  for (int i = 0; i < 4; ++i)
#pragma unroll
    for (int c = 0; c < 8; ++c) acc[i][c] = 0.f;

  int r[4];
#pragma unroll
  for (int i = 0; i < 4; ++i) {
    r[i] = rbase + i;
    if (r[i] > nrows - 1) r[i] = nrows - 1;  // clamp; discarded at store
  }

  const float4* M4 = (const float4*)M;
  for (int k4 = 0; k4 < D / 4; ++k4) {
    float4 mv[4];
#pragma unroll
    for (int i = 0; i < 4; ++i) mv[i] = M4[r[i] * (D / 4) + k4];
    float mk[4][4];
#pragma unroll
    for (int i = 0; i < 4; ++i) {
      mk[i][0] = mv[i].x; mk[i][1] = mv[i].y; mk[i][2] = mv[i].z; mk[i][3] = mv[i].w;
    }
#pragma unroll
    for (int kk = 0; kk < 4; ++kk) {
      const float* wrow = Wl + (k4 * 4 + kk) * D + c0;
      float4 w0 = *(const float4*)(wrow);
      float4 w1 = *(const float4*)(wrow + 4);
      float wv[8] = {w0.x, w0.y, w0.z, w0.w, w1.x, w1.y, w1.z, w1.w};
#pragma unroll
      for (int i = 0; i < 4; ++i)
#pragma unroll
        for (int c = 0; c < 8; ++c) acc[i][c] += mk[i][kk] * wv[c];
    }
  }

  __syncthreads();  // all in-place reads of M complete before writes

#pragma unroll
  for (int i = 0; i < 4; ++i) {
    int rr = rbase + i;
    if (rr < nrows) {
      float ps = postscale ? postscale[rr] : 1.f;
      float4 o0, o1;
      o0.x = fmaxf(acc[i][0] + bias[c0 + 0], 0.f) * ps;
      o0.y = fmaxf(acc[i][1] + bias[c0 + 1], 0.f) * ps;
      o0.z = fmaxf(acc[i][2] + bias[c0 + 2], 0.f) * ps;
      o0.w = fmaxf(acc[i][3] + bias[c0 + 3], 0.f) * ps;
      o1.x = fmaxf(acc[i][4] + bias[c0 + 4], 0.f) * ps;
      o1.y = fmaxf(acc[i][5] + bias[c0 + 5], 0.f) * ps;
      o1.z = fmaxf(acc[i][6] + bias[c0 + 6], 0.f) * ps;
      o1.w = fmaxf(acc[i][7] + bias[c0 + 7], 0.f) * ps;
      *(float4*)(out + rr * D + c0)     = o0;
      *(float4*)(out + rr * D + c0 + 4) = o1;
    }
  }
}

// ------------------------------------------------------------------- score
// One wave (64 lanes) per score edge; lane handles features {lane, lane+64}.
__global__ void score_kernel(const float* __restrict__ H, const int* __restrict__ ss,
                             const int* __restrict__ sd, float* __restrict__ out, int ES) {
  int wid = (int)((blockIdx.x * blockDim.x + threadIdx.x) >> 6);
  int lane = threadIdx.x & 63;
  if (wid >= ES) return;
  int a = ss[wid], b = sd[wid];
  const float* pa = H + (size_t)a * D;
  const float* pb = H + (size_t)b * D;
  float p = pa[lane] * pb[lane] + pa[lane + 64] * pb[lane + 64];
#pragma unroll
  for (int off = 32; off > 0; off >>= 1) p += __shfl_xor(p, off, 64);
  if (lane == 0) out[wid] = p;
}

// ------------------------------------------------------------------ launch
extern "C" void kernel_launch(void* const* d_in, const int* in_sizes, int n_in,
                              void* d_out, int out_size, void* d_ws, size_t ws_size,
                              hipStream_t stream) {
  const float* x   = (const float*)d_in[0];
  const int* esrc  = (const int*)d_in[1];
  const int* edst  = (const int*)d_in[2];
  const int* ssrc  = (const int*)d_in[3];
  const int* sdst  = (const int*)d_in[4];
  const float* W1  = (const float*)d_in[5];
  const float* b1  = (const float*)d_in[6];
  const float* W2  = (const float*)d_in[7];
  const float* b2  = (const float*)d_in[8];
  float* out = (float*)d_out;

  const int N  = in_sizes[0] / D;  // 50000
  const int E  = in_sizes[1];      // 800000
  const int ES = in_sizes[3];      // 200000
  const int NBUCK = (N + 63) >> 6; // 782

  char* w = (char*)d_ws;
  auto take = [&](size_t bytes) {
    char* p = w;
    w += (bytes + 255) & ~(size_t)255;
    return p;
  };
  float* rs_out = (float*)take((size_t)N * 4);
  float* rs_in  = (float*)take((size_t)N * 4);
  int* row_ptr  = (int*)take((size_t)(N + 1) * 4);
  unsigned* gcnt = (unsigned*)take((size_t)2 * MAXBUCK * 4);
  int* base_dst = (int*)take((size_t)(MAXBUCK + 1) * 4);
  int* base_src = (int*)take((size_t)(MAXBUCK + 1) * 4);
  int* gcur_dst = (int*)take((size_t)MAXBUCK * 4);
  int* gcur_src = (int*)take((size_t)MAXBUCK * 4);
  int* csr_src  = (int*)take((size_t)E * 4);
  float* bufA   = (float*)take((size_t)N * D * 4);
  float* bufB   = (float*)take((size_t)N * D * 4);

  unsigned* gcnt_dst = gcnt;
  unsigned* gcnt_src = gcnt + MAXBUCK;
  // bucket arrays (E*8 + E*4 = 9.6 MB) alias into bufA (25.6 MB): fully
  // consumed by phaseD before the first spmm writes bufA.
  unsigned long long* bkt = (unsigned long long*)bufA;
  int* bkt_src = (int*)(bufA + (size_t)E * 2);  // E*2 floats = E*8 bytes

  const int chunk = (E + NBLK_BIN - 1) / NBLK_BIN;

  // ---- CSR + degrees via two-level LDS-aggregated counting sort
  zero_u32<<<8, 256, 0, stream>>>(gcnt, 2 * MAXBUCK);
  phaseA<<<NBLK_BIN, 256, 0, stream>>>(esrc, edst, gcnt_dst, gcnt_src, E, NBUCK, chunk);
  phaseB<<<1, 1024, 0, stream>>>(gcnt_dst, gcnt_src, base_dst, base_src,
                                 gcur_dst, gcur_src, row_ptr, N, E, NBUCK);
  phaseC<<<NBLK_BIN, 256, 0, stream>>>(esrc, edst, gcur_dst, gcur_src,
                                       bkt, bkt_src, E, NBUCK, chunk);
  // Fused: dst histogram/scatter + src histogram + prescale x -> bufB
  phaseD<<<NBUCK, 256, 0, stream>>>(bkt, base_dst, bkt_src, base_src,
                                    row_ptr, rs_in, rs_out, csr_src,
                                    x, bufB, N);

  // Layer 1: SpMM(x_prescaled) -> bufA; GEMM in-place, epilogue pre-scales
  // by rs_out so h1 is ready for layer-2 gather.
  spmm<<<(N + 3) / 4, 256, 0, stream>>>(bufB, row_ptr, csr_src, rs_in, bufA, N);
  gemm_bias_relu<<<(N + 63) / 64, 256, 0, stream>>>(bufA, W1, b1, rs_out, bufA, N);

  // Layer 2: SpMM(h1_prescaled) -> bufB; GEMM in-place, no post-scale.
  spmm<<<(N + 3) / 4, 256, 0, stream>>>(bufA, row_ptr, csr_src, rs_in, bufB, N);
  gemm_bias_relu<<<(N + 63) / 64, 256, 0, stream>>>(bufB, W2, b2, nullptr, bufB, N);

  score_kernel<<<(ES + 3) / 4, 256, 0, stream>>>(bufB, ssrc, sdst, out, ES);
}